// Round 14
// baseline (341.122 us; speedup 1.0000x reference)
//
#include <hip/hip_runtime.h>
#include <hip/hip_bf16.h>
#include <stdint.h>

#define NIMG 96
#define N 512
#define IMG (N*N)
#define OUT_PLANE ((long long)NIMG * IMG)

typedef __attribute__((ext_vector_type(8))) _Float16 f16x8;
typedef __attribute__((ext_vector_type(4))) float f32x4;
typedef unsigned short u16;

__device__ __forceinline__ u16 f2h(float v) {
    _Float16 h = (_Float16)v;
    return __builtin_bit_cast(u16, h);
}

__device__ __forceinline__ void gload16(const void* g, void* l) {
    __builtin_amdgcn_global_load_lds(
        (const __attribute__((address_space(1))) void*)g,
        (__attribute__((address_space(3))) void*)l, 16, 0, 0);
}

// ---------------------------------------------------------------------------
// conv_x: x fp32 -> Xcm f16 col-major; outLL = x (all-ones mask = identity).
// Blocks with flat id < 1024 also build D (f16, row- and col-major).
// ---------------------------------------------------------------------------
__global__ __launch_bounds__(256) void conv_x(const float* __restrict__ x,
                                              u16* __restrict__ Xcm,
                                              float* __restrict__ outLL,
                                              u16* __restrict__ Drm,
                                              u16* __restrict__ Dcm) {
    const int bid = blockIdx.x + (blockIdx.y << 4) + (blockIdx.z << 8);
    if (bid < 1024) {
        int idx = (bid << 8) + threadIdx.x;
        int k = idx >> 9, m = idx & 511;
        int r = ((2 * m + 1) * k) & 2047;          // exact angle reduction mod 4N
        float c = cospif((float)r * (1.0f / 1024.0f));
        float s = (k == 0) ? 0.04419417382415922f : 0.0625f;
        u16 h = f2h(c * s);
        Drm[(k << 9) + m] = h;
        Dcm[(m << 9) + k] = h;
    }

    __shared__ float t[32][33];
    const long long base = (long long)blockIdx.z * IMG;
    const int r0 = blockIdx.y * 32, c0 = blockIdx.x * 32;
    const int tr = threadIdx.x >> 3;
    const int tc = (threadIdx.x & 7) * 4;
    float4 v = *(const float4*)&x[base + (long long)(r0 + tr) * N + c0 + tc];
    *(float4*)&outLL[base + (long long)(r0 + tr) * N + c0 + tc] = v;
    t[tr][tc + 0] = v.x; t[tr][tc + 1] = v.y;
    t[tr][tc + 2] = v.z; t[tr][tc + 3] = v.w;
    __syncthreads();
    ushort4 h;
    h.x = f2h(t[tc + 0][tr]); h.y = f2h(t[tc + 1][tr]);
    h.z = f2h(t[tc + 2][tr]); h.w = f2h(t[tc + 3][tr]);
    *(ushort4*)&Xcm[base + (long long)(c0 + tr) * N + r0 + tc] = h;
}

// ===========================================================================
// Proven GEMM engine (R6/R11/R13): 128x128 tile, BK=32, 4 waves, dbuf LDS,
// global_load_lds width-16 staging, mfma_f32_16x16x32_f16, 2-barrier loop.
// Multi-pass safety (R13-proven): nb is even for all K here, so the final
// compute of a pass reads buf1 while the next pass's first stage writes buf0;
// the prologue barrier then orders the buf1 re-stage. Inter-pass
// __syncthreads kept as belt-and-braces.
// C = A(row-major) * B(col-major storage: stored[n][k] = op(B)[k][n]).
// ===========================================================================
#define GEMM_DECLS                                                         \
    const int tid = threadIdx.x;                                           \
    const int wave = tid >> 6;                                             \
    const int lane = tid & 63;                                             \
    const int srow = lane >> 2;                                            \
    const int sc8  = (lane & 3) * 8;                                       \
    const int war  = wave * 32;                                            \
    const int fr   = lane & 15;                                            \
    const int kg8  = (lane >> 4) * 8;                                      \
    const int wr   = (wave >> 1) * 64;                                     \
    const int wc   = (wave & 1) * 64;                                      \
    const int rb   = (lane >> 4) * 4;                                      \
    int aoff[4], boff[4];                                                  \
    _Pragma("unroll")                                                      \
    for (int i = 0; i < 4; ++i) {                                          \
        aoff[i] = (wr + i * 16 + fr) * 32 + kg8;                           \
        boff[i] = (wc + i * 16 + fr) * 32 + kg8;                           \
    }                                                                      \
    f32x4 acc[4][4];                                                       \
    _Pragma("unroll")                                                      \
    for (int i = 0; i < 4; ++i)                                            \
        _Pragma("unroll")                                                  \
        for (int j = 0; j < 4; ++j)                                        \
            acc[i][j] = (f32x4){0.0f, 0.0f, 0.0f, 0.0f};

#define GEMM_LOOP(Ab, lda, Bb, ldb, Keff)                                  \
    {                                                                      \
        auto stage = [&](int buf, int k0) {                                \
            _Pragma("unroll")                                              \
            for (int i = 0; i < 2; ++i) {                                  \
                int r = war + i * 16;                                      \
                gload16((Ab) + (long long)(m0 + r + srow) * (lda) + k0 + sc8, &As[buf][r * 32]); \
                gload16((Bb) + (long long)(n0 + r + srow) * (ldb) + k0 + sc8, &Bs[buf][r * 32]); \
            }                                                              \
        };                                                                 \
        auto compute = [&](int buf) {                                      \
            f16x8 af[4], bf[4];                                            \
            _Pragma("unroll")                                              \
            for (int i = 0; i < 4; ++i) af[i] = *(const f16x8*)&As[buf][aoff[i]]; \
            _Pragma("unroll")                                              \
            for (int j = 0; j < 4; ++j) bf[j] = *(const f16x8*)&Bs[buf][boff[j]]; \
            _Pragma("unroll")                                              \
            for (int i = 0; i < 4; ++i)                                    \
                _Pragma("unroll")                                          \
                for (int j = 0; j < 4; ++j)                                \
                    acc[i][j] = __builtin_amdgcn_mfma_f32_16x16x32_f16(af[i], bf[j], acc[i][j], 0, 0, 0); \
        };                                                                 \
        const int nb = (Keff) >> 5;                                        \
        stage(0, 0);                                                       \
        __syncthreads();                                                   \
        int cur = 0;                                                       \
        for (int t = 0; t < nb - 1; ++t) {                                 \
            stage(cur ^ 1, (t + 1) * 32);                                  \
            compute(cur);                                                  \
            __syncthreads();                                               \
            cur ^= 1;                                                      \
        }                                                                  \
        compute(cur);                                                      \
    }

// ---------------------------------------------------------------------------
// gemm16<EPI, NPASS>:
//  EPI 1 = f16 row-major; NPASS m-tiles per block (grid y = m-pairs).
//  EPI 3 = f16 col-major + tri511 mask + fused Y2/Y3; compact 10-tile LUT,
//          NPASS=1.
// ---------------------------------------------------------------------------
template<int EPI, int NPASS>
__global__ __launch_bounds__(256) void gemm16(
    const u16* __restrict__ A, long long sA, int lda,
    const u16* __restrict__ B, long long sB, int ldb,
    void* __restrict__ Cv, long long sC, int ldc,
    int K, int trilim,
    u16* __restrict__ Y2, u16* __restrict__ Y3)
{
    __shared__ u16 As[2][128 * 32];
    __shared__ u16 Bs[2][128 * 32];
    const int bz = blockIdx.z;
    int m0base, n0;
    if (EPI == 3) {
        // compact LUT over live tiles of the tri511 mask (ti+tj <= 3)
        int id = blockIdx.x, ti, tj;
        if (id < 4)      { ti = 0; tj = id; }
        else if (id < 7) { ti = 1; tj = id - 4; }
        else if (id < 9) { ti = 2; tj = id - 7; }
        else             { ti = 3; tj = 0; }
        m0base = ti * 128; n0 = tj * 128;
    } else {
        m0base = blockIdx.y * 128 * NPASS;
        n0 = blockIdx.x * 128;
    }

    const u16* __restrict__ Ab = A + (long long)bz * sA;
    const u16* __restrict__ Bb = B + (long long)bz * sB;

    for (int pass = 0; pass < NPASS; ++pass) {
        const int m0 = m0base + pass * 128;
        GEMM_DECLS
        GEMM_LOOP(Ab, lda, Bb, ldb, K)

        if (EPI == 1) {
            u16* Cb = (u16*)Cv + (long long)bz * sC;
            #pragma unroll
            for (int i = 0; i < 4; ++i)
                #pragma unroll
                for (int j = 0; j < 4; ++j) {
                    int r = m0 + wr + i * 16 + rb;
                    int c = n0 + wc + j * 16 + fr;
                    #pragma unroll
                    for (int g = 0; g < 4; ++g)
                        Cb[(long long)(r + g) * ldc + c] = f2h(acc[i][j][g]);
                }
        } else {
            u16* Cb = (u16*)Cv + (long long)bz * sC;
            u16* Y2b = Y2 + (long long)bz * (256 * 256);
            u16* Y3b = Y3 + (long long)bz * (128 * 128);
            const bool doY2 = (m0 + n0 < 256);    // Y2 zero quadrant never read (kcap)
            #pragma unroll
            for (int i = 0; i < 4; ++i)
                #pragma unroll
                for (int j = 0; j < 4; ++j) {
                    int r = m0 + wr + i * 16 + rb;
                    int c = n0 + wc + j * 16 + fr;
                    float v0 = ((r + 0) + c <= trilim) ? acc[i][j][0] : 0.0f;
                    float v1 = ((r + 1) + c <= trilim) ? acc[i][j][1] : 0.0f;
                    float v2 = ((r + 2) + c <= trilim) ? acc[i][j][2] : 0.0f;
                    float v3 = ((r + 3) + c <= trilim) ? acc[i][j][3] : 0.0f;
                    ushort4 h;
                    h.x = f2h(v0); h.y = f2h(v1); h.z = f2h(v2); h.w = f2h(v3);
                    *(ushort4*)&Cb[(long long)c * ldc + r] = h;   // col-major 8B store
                    if (doY2 && r < 256 && c < 256) {
                        ushort4 h2;
                        h2.x = ((r + 0) + c <= 255) ? h.x : (u16)0;
                        h2.y = ((r + 1) + c <= 255) ? h.y : (u16)0;
                        h2.z = ((r + 2) + c <= 255) ? h.z : (u16)0;
                        h2.w = ((r + 3) + c <= 255) ? h.w : (u16)0;
                        *(ushort4*)&Y2b[(long long)c * 256 + r] = h2;
                    }
                    if (r < 128 && c < 128) {
                        ushort4 h3;
                        h3.x = ((r + 0) + c <= 127) ? h.x : (u16)0;
                        h3.y = ((r + 1) + c <= 127) ? h.y : (u16)0;
                        h3.z = ((r + 2) + c <= 127) ? h.z : (u16)0;
                        h3.w = ((r + 3) + c <= 127) ? h.w : (u16)0;
                        *(ushort4*)&Y3b[(long long)c * 128 + r] = h3;
                    }
                }
        }
        if (pass + 1 < NPASS) __syncthreads();
    }
}

// ---------------------------------------------------------------------------
// invA: merged S3/S5/S7, 2-pass over n0 (Keff depends only on m0 -> constant
// across the pass pair). Flat blockIdx.x in [0,14):
//  [0,8)  = S3: m0=(id>>1)*128, n0base=(id&1)*256, Keff=512-m0
//  [8,12) = S5: m0=(t>>1)*128,  n0base=(t&1)*256,  Keff=256-m0
//  [12,14)= S7: m0=0,           n0base=t*256,      Keff=128
// All write f16 col-major (= U* row-major).
// ---------------------------------------------------------------------------
__global__ __launch_bounds__(256) void invA(
    const u16* __restrict__ Ycm, const u16* __restrict__ Y2,
    const u16* __restrict__ Y3, const u16* __restrict__ Dcm,
    u16* __restrict__ U, u16* __restrict__ U2, u16* __restrict__ U3)
{
    __shared__ u16 As[2][128 * 32];
    __shared__ u16 Bs[2][128 * 32];
    const int bz = blockIdx.z;
    const int id = blockIdx.x;

    const u16* __restrict__ Ab;
    u16* __restrict__ Cb;
    int lda, ldc, Keff, m0, n0base;
    if (id < 8) {             // S3: U^T = Ym^T @ D   (M=512, K=512-m0)
        m0 = (id >> 1) * 128; n0base = (id & 1) * 256;
        Ab = Ycm + (long long)bz * IMG;     lda = 512;
        Cb = U   + (long long)bz * IMG;     ldc = 512;
        Keff = 512 - m0;
    } else if (id < 12) {     // S5: U2^T = Y2^T @ D[:256,:]  (M=256, K=256-m0)
        int t = id - 8;
        m0 = (t >> 1) * 128; n0base = (t & 1) * 256;
        Ab = Y2 + (long long)bz * 65536;    lda = 256;
        Cb = U2 + (long long)bz * 131072;   ldc = 256;
        Keff = 256 - m0;
    } else {                  // S7: U3^T = Y3^T @ D[:128,:]  (M=128, K=128)
        int t = id - 12;
        m0 = 0;              n0base = t * 256;
        Ab = Y3 + (long long)bz * 16384;    lda = 128;
        Cb = U3 + (long long)bz * 65536;    ldc = 128;
        Keff = 128;
    }
    const u16* __restrict__ Bb = Dcm;
    const int ldb = 512;

    for (int pass = 0; pass < 2; ++pass) {
        const int n0 = n0base + pass * 128;
        GEMM_DECLS
        GEMM_LOOP(Ab, lda, Bb, ldb, Keff)

        #pragma unroll
        for (int i = 0; i < 4; ++i)
            #pragma unroll
            for (int j = 0; j < 4; ++j) {
                int r = m0 + wr + i * 16 + rb;
                int c = n0 + wc + j * 16 + fr;
                ushort4 h;
                h.x = f2h(acc[i][j][0]); h.y = f2h(acc[i][j][1]);
                h.z = f2h(acc[i][j][2]); h.w = f2h(acc[i][j][3]);
                *(ushort4*)&Cb[(long long)c * ldc + r] = h;
            }
        if (pass == 0) __syncthreads();
    }
}

// ---------------------------------------------------------------------------
// invC: merged S6/S8/S4, all 2-pass over m. fp32 row-major out.
// Flat blockIdx.x in [0,24): [0,8)=S6 (K=256), [8,16)=S8 (K=128),
// [16,24)=S4 (K=512). m0base=(sub>>2)*256, n0=(sub&3)*128.
// ---------------------------------------------------------------------------
__global__ __launch_bounds__(256) void invC(
    const u16* __restrict__ U2, const u16* __restrict__ U3,
    const u16* __restrict__ U, const u16* __restrict__ Dcm,
    float* __restrict__ outHL, float* __restrict__ outLH,
    float* __restrict__ outHH)
{
    __shared__ u16 As[2][128 * 32];
    __shared__ u16 Bs[2][128 * 32];
    const int bz = blockIdx.z;
    const int id = blockIdx.x;

    const u16* __restrict__ Ab;
    float* __restrict__ Cb;
    int lda, Keff, m0base, n0;
    if (id < 8) {             // S6: HL
        m0base = (id >> 2) * 256; n0 = (id & 3) * 128;
        Ab = U2 + (long long)bz * 131072;  lda = 256; Keff = 256;
        Cb = outHL + (long long)bz * IMG;
    } else if (id < 16) {     // S8: LH
        int t = id - 8;
        m0base = (t >> 2) * 256; n0 = (t & 3) * 128;
        Ab = U3 + (long long)bz * 65536;   lda = 128; Keff = 128;
        Cb = outLH + (long long)bz * IMG;
    } else {                  // S4: HH
        int t = id - 16;
        m0base = (t >> 2) * 256; n0 = (t & 3) * 128;
        Ab = U + (long long)bz * IMG;      lda = 512; Keff = 512;
        Cb = outHH + (long long)bz * IMG;
    }
    const u16* __restrict__ Bb = Dcm;
    const int ldb = 512;
    const int ldc = 512;

    for (int pass = 0; pass < 2; ++pass) {
        const int m0 = m0base + pass * 128;
        GEMM_DECLS
        GEMM_LOOP(Ab, lda, Bb, ldb, Keff)

        #pragma unroll
        for (int i = 0; i < 4; ++i)
            #pragma unroll
            for (int j = 0; j < 4; ++j) {
                int r = m0 + wr + i * 16 + rb;
                int c = n0 + wc + j * 16 + fr;
                #pragma unroll
                for (int g = 0; g < 4; ++g)
                    Cb[(long long)(r + g) * ldc + c] = acc[i][j][g];
            }
        if (pass == 0) __syncthreads();
    }
}

// ---------------------------------------------------------------------------
// Orchestration (5 dispatches): conv -> S1 -> S2 -> invA -> invC.
// ws layout (ws_size ~1.5GiB per poison-fill evidence; we use 148MiB):
//   Drm @0 | Dcm @512K | Xcm/Ycm @1MiB (48MiB) |
//   reg @49MiB (48MiB): T1 (S1->S2) then U (invA->invC) |
//   Y2 @97MiB | Y3 @109MiB | U2 @112MiB | U3 @136MiB
// Race-freedom: invA reads Ycm/Y2/Y3, writes U/U2/U3 (disjoint); invC reads
// U/U2/U3 (read-only), writes the three d_out quarters (disjoint).
// ---------------------------------------------------------------------------
extern "C" void kernel_launch(void* const* d_in, const int* in_sizes, int n_in,
                              void* d_out, int out_size, void* d_ws, size_t ws_size,
                              hipStream_t stream) {
    const float* x = (const float*)d_in[0];
    float* out = (float*)d_out;
    float* outLL = out + 0 * OUT_PLANE;
    float* outLH = out + 1 * OUT_PLANE;
    float* outHL = out + 2 * OUT_PLANE;
    float* outHH = out + 3 * OUT_PLANE;

    char* ws = (char*)d_ws;
    u16* Drm = (u16*)(ws);
    u16* Dcm = (u16*)(ws + 524288);
    u16* Xcm = (u16*)(ws + 1048576);
    u16* Ycm = Xcm;
    char* reg = ws + 51380224;
    u16* T1 = (u16*)reg;
    u16* U  = (u16*)reg;
    u16* Y2 = (u16*)(ws + 101711872);      // 96*256*256 f16 = 12 MiB
    u16* Y3 = (u16*)(ws + 114294784);      // 96*128*128 f16 = 3 MiB
    u16* U2 = (u16*)(ws + 117440512);      // 96*512*256 f16 = 24 MiB
    u16* U3 = (u16*)(ws + 142606336);      // 96*512*128 f16 = 12 MiB

    const long long S = IMG;
    const int BIG = 1 << 30;

    // conv + D-build + LL copy
    conv_x<<<dim3(16, 16, NIMG), 256, 0, stream>>>(x, Xcm, outLL, Drm, Dcm);

    // S1: T1 = D @ X -> f16 row-major (2 m-tiles per block)
    gemm16<1, 2><<<dim3(4, 2, NIMG), 256, 0, stream>>>(
        Drm, 0, 512, Xcm, S, 512, T1, S, 512, 512, BIG, nullptr, nullptr);
    // S2: Y = T1 @ D^T -> Ycm (tri511) + Y2/Y3; compact grid (10 live tiles)
    gemm16<3, 1><<<dim3(10, 1, NIMG), 256, 0, stream>>>(
        T1, S, 512, Drm, 0, 512, Ycm, S, 512, 512, 511, Y2, Y3);
    // invA: S3 + S5 + S7 (2-pass over n) -> U, U2, U3
    invA<<<dim3(14, 1, NIMG), 256, 0, stream>>>(Ycm, Y2, Y3, Dcm, U, U2, U3);
    // invC: S6 + S8 + S4 (all 2-pass over m) -> outHL, outLH, outHH
    invC<<<dim3(24, 1, NIMG), 256, 0, stream>>>(U2, U3, U, Dcm, outHL, outLH, outHH);
}

// Round 15
// 321.788 us; speedup vs baseline: 1.0601x; 1.0601x over previous
//
#include <hip/hip_runtime.h>
#include <hip/hip_bf16.h>
#include <stdint.h>

#define NIMG 96
#define N 512
#define IMG (N*N)
#define OUT_PLANE ((long long)NIMG * IMG)

typedef __attribute__((ext_vector_type(8))) _Float16 f16x8;
typedef __attribute__((ext_vector_type(4))) float f32x4;
typedef unsigned short u16;

__device__ __forceinline__ u16 f2h(float v) {
    _Float16 h = (_Float16)v;
    return __builtin_bit_cast(u16, h);
}

__device__ __forceinline__ void gload16(const void* g, void* l) {
    __builtin_amdgcn_global_load_lds(
        (const __attribute__((address_space(1))) void*)g,
        (__attribute__((address_space(3))) void*)l, 16, 0, 0);
}

// ---------------------------------------------------------------------------
// conv_x: x fp32 -> Xcm f16 col-major; outLL = x (all-ones mask = identity).
// Blocks with flat id < 1024 also build D (f16, row- and col-major).
// ---------------------------------------------------------------------------
__global__ __launch_bounds__(256) void conv_x(const float* __restrict__ x,
                                              u16* __restrict__ Xcm,
                                              float* __restrict__ outLL,
                                              u16* __restrict__ Drm,
                                              u16* __restrict__ Dcm) {
    const int bid = blockIdx.x + (blockIdx.y << 4) + (blockIdx.z << 8);
    if (bid < 1024) {
        int idx = (bid << 8) + threadIdx.x;
        int k = idx >> 9, m = idx & 511;
        int r = ((2 * m + 1) * k) & 2047;          // exact angle reduction mod 4N
        float c = cospif((float)r * (1.0f / 1024.0f));
        float s = (k == 0) ? 0.04419417382415922f : 0.0625f;
        u16 h = f2h(c * s);
        Drm[(k << 9) + m] = h;
        Dcm[(m << 9) + k] = h;
    }

    __shared__ float t[32][33];
    const long long base = (long long)blockIdx.z * IMG;
    const int r0 = blockIdx.y * 32, c0 = blockIdx.x * 32;
    const int tr = threadIdx.x >> 3;
    const int tc = (threadIdx.x & 7) * 4;
    float4 v = *(const float4*)&x[base + (long long)(r0 + tr) * N + c0 + tc];
    *(float4*)&outLL[base + (long long)(r0 + tr) * N + c0 + tc] = v;
    t[tr][tc + 0] = v.x; t[tr][tc + 1] = v.y;
    t[tr][tc + 2] = v.z; t[tr][tc + 3] = v.w;
    __syncthreads();
    ushort4 h;
    h.x = f2h(t[tc + 0][tr]); h.y = f2h(t[tc + 1][tr]);
    h.z = f2h(t[tc + 2][tr]); h.w = f2h(t[tc + 3][tr]);
    *(ushort4*)&Xcm[base + (long long)(c0 + tr) * N + r0 + tc] = h;
}

// ===========================================================================
// Proven GEMM engine (R6/R11/R13): 128x128 tile, BK=32, 4 waves, dbuf LDS,
// global_load_lds width-16 staging, mfma_f32_16x16x32_f16, 2-barrier loop.
// This round: __launch_bounds__(256, 4) on the GEMM kernels — min 4 waves/EU
// caps the allocator at 128 VGPR -> 4 blocks/CU (vs ~3 at the m97-analog's
// 164 VGPR), +33% resident waves to hide the barrier vmcnt drain.
// C = A(row-major) * B(col-major storage: stored[n][k] = op(B)[k][n]).
// ===========================================================================
#define GEMM_DECLS                                                         \
    const int tid = threadIdx.x;                                           \
    const int wave = tid >> 6;                                             \
    const int lane = tid & 63;                                             \
    const int srow = lane >> 2;                                            \
    const int sc8  = (lane & 3) * 8;                                       \
    const int war  = wave * 32;                                            \
    const int fr   = lane & 15;                                            \
    const int kg8  = (lane >> 4) * 8;                                      \
    const int wr   = (wave >> 1) * 64;                                     \
    const int wc   = (wave & 1) * 64;                                      \
    const int rb   = (lane >> 4) * 4;                                      \
    int aoff[4], boff[4];                                                  \
    _Pragma("unroll")                                                      \
    for (int i = 0; i < 4; ++i) {                                          \
        aoff[i] = (wr + i * 16 + fr) * 32 + kg8;                           \
        boff[i] = (wc + i * 16 + fr) * 32 + kg8;                           \
    }                                                                      \
    f32x4 acc[4][4];                                                       \
    _Pragma("unroll")                                                      \
    for (int i = 0; i < 4; ++i)                                            \
        _Pragma("unroll")                                                  \
        for (int j = 0; j < 4; ++j)                                        \
            acc[i][j] = (f32x4){0.0f, 0.0f, 0.0f, 0.0f};

#define GEMM_LOOP(Ab, lda, Bb, ldb, Keff)                                  \
    {                                                                      \
        auto stage = [&](int buf, int k0) {                                \
            _Pragma("unroll")                                              \
            for (int i = 0; i < 2; ++i) {                                  \
                int r = war + i * 16;                                      \
                gload16((Ab) + (long long)(m0 + r + srow) * (lda) + k0 + sc8, &As[buf][r * 32]); \
                gload16((Bb) + (long long)(n0 + r + srow) * (ldb) + k0 + sc8, &Bs[buf][r * 32]); \
            }                                                              \
        };                                                                 \
        auto compute = [&](int buf) {                                      \
            f16x8 af[4], bf[4];                                            \
            _Pragma("unroll")                                              \
            for (int i = 0; i < 4; ++i) af[i] = *(const f16x8*)&As[buf][aoff[i]]; \
            _Pragma("unroll")                                              \
            for (int j = 0; j < 4; ++j) bf[j] = *(const f16x8*)&Bs[buf][boff[j]]; \
            _Pragma("unroll")                                              \
            for (int i = 0; i < 4; ++i)                                    \
                _Pragma("unroll")                                          \
                for (int j = 0; j < 4; ++j)                                \
                    acc[i][j] = __builtin_amdgcn_mfma_f32_16x16x32_f16(af[i], bf[j], acc[i][j], 0, 0, 0); \
        };                                                                 \
        const int nb = (Keff) >> 5;                                        \
        stage(0, 0);                                                       \
        __syncthreads();                                                   \
        int cur = 0;                                                       \
        for (int t = 0; t < nb - 1; ++t) {                                 \
            stage(cur ^ 1, (t + 1) * 32);                                  \
            compute(cur);                                                  \
            __syncthreads();                                               \
            cur ^= 1;                                                      \
        }                                                                  \
        compute(cur);                                                      \
    }

// ---------------------------------------------------------------------------
// gemm16: EPI 1 = f16 row-major (grid y/x tiles);
//         3 = f16 col-major + tri511 mask + fused Y2/Y3 sub-blocks.
//             Launched with a COMPACT grid of the 10 live tiles.
// ---------------------------------------------------------------------------
template<int EPI>
__global__ __launch_bounds__(256, 4) void gemm16(
    const u16* __restrict__ A, long long sA, int lda,
    const u16* __restrict__ B, long long sB, int ldb,
    void* __restrict__ Cv, long long sC, int ldc,
    int K, int trilim,
    u16* __restrict__ Y2, u16* __restrict__ Y3)
{
    __shared__ u16 As[2][128 * 32];
    __shared__ u16 Bs[2][128 * 32];
    const int bz = blockIdx.z;
    int m0, n0;
    if (EPI == 3) {
        // compact LUT over live tiles of the tri511 mask (ti+tj <= 3)
        int id = blockIdx.x, ti, tj;
        if (id < 4)      { ti = 0; tj = id; }
        else if (id < 7) { ti = 1; tj = id - 4; }
        else if (id < 9) { ti = 2; tj = id - 7; }
        else             { ti = 3; tj = 0; }
        m0 = ti * 128; n0 = tj * 128;
    } else {
        m0 = blockIdx.y * 128;
        n0 = blockIdx.x * 128;
    }

    const u16* __restrict__ Ab = A + (long long)bz * sA;
    const u16* __restrict__ Bb = B + (long long)bz * sB;

    GEMM_DECLS
    GEMM_LOOP(Ab, lda, Bb, ldb, K)

    if (EPI == 1) {
        u16* Cb = (u16*)Cv + (long long)bz * sC;
        #pragma unroll
        for (int i = 0; i < 4; ++i)
            #pragma unroll
            for (int j = 0; j < 4; ++j) {
                int r = m0 + wr + i * 16 + rb;
                int c = n0 + wc + j * 16 + fr;
                #pragma unroll
                for (int g = 0; g < 4; ++g)
                    Cb[(long long)(r + g) * ldc + c] = f2h(acc[i][j][g]);
            }
    } else {
        u16* Cb = (u16*)Cv + (long long)bz * sC;
        u16* Y2b = Y2 + (long long)bz * (256 * 256);
        u16* Y3b = Y3 + (long long)bz * (128 * 128);
        const bool doY2 = (m0 + n0 < 256);        // Y2 zero quadrant never read (kcap)
        #pragma unroll
        for (int i = 0; i < 4; ++i)
            #pragma unroll
            for (int j = 0; j < 4; ++j) {
                int r = m0 + wr + i * 16 + rb;
                int c = n0 + wc + j * 16 + fr;
                float v0 = ((r + 0) + c <= trilim) ? acc[i][j][0] : 0.0f;
                float v1 = ((r + 1) + c <= trilim) ? acc[i][j][1] : 0.0f;
                float v2 = ((r + 2) + c <= trilim) ? acc[i][j][2] : 0.0f;
                float v3 = ((r + 3) + c <= trilim) ? acc[i][j][3] : 0.0f;
                ushort4 h;
                h.x = f2h(v0); h.y = f2h(v1); h.z = f2h(v2); h.w = f2h(v3);
                *(ushort4*)&Cb[(long long)c * ldc + r] = h;   // col-major 8B store
                if (doY2 && r < 256 && c < 256) {
                    ushort4 h2;
                    h2.x = ((r + 0) + c <= 255) ? h.x : (u16)0;
                    h2.y = ((r + 1) + c <= 255) ? h.y : (u16)0;
                    h2.z = ((r + 2) + c <= 255) ? h.z : (u16)0;
                    h2.w = ((r + 3) + c <= 255) ? h.w : (u16)0;
                    *(ushort4*)&Y2b[(long long)c * 256 + r] = h2;
                }
                if (r < 128 && c < 128) {
                    ushort4 h3;
                    h3.x = ((r + 0) + c <= 127) ? h.x : (u16)0;
                    h3.y = ((r + 1) + c <= 127) ? h.y : (u16)0;
                    h3.z = ((r + 2) + c <= 127) ? h.z : (u16)0;
                    h3.w = ((r + 3) + c <= 127) ? h.w : (u16)0;
                    *(ushort4*)&Y3b[(long long)c * 128 + r] = h3;
                }
            }
    }
}

// ---------------------------------------------------------------------------
// invA: merged S3/S5/S7. Flat blockIdx.x in [0,28): [0,16)=S3, [16,24)=S5,
// [24,28)=S7. All write f16 col-major (= U* row-major). A anti-triangular ->
// K early stop (Keff).
// ---------------------------------------------------------------------------
__global__ __launch_bounds__(256, 4) void invA(
    const u16* __restrict__ Ycm, const u16* __restrict__ Y2,
    const u16* __restrict__ Y3, const u16* __restrict__ Dcm,
    u16* __restrict__ U, u16* __restrict__ U2, u16* __restrict__ U3)
{
    __shared__ u16 As[2][128 * 32];
    __shared__ u16 Bs[2][128 * 32];
    const int bz = blockIdx.z;
    const int id = blockIdx.x;

    const u16* __restrict__ Ab;
    u16* __restrict__ Cb;
    int lda, ldc, Keff, m0, n0;
    if (id < 16) {            // S3: U^T = Ym^T @ D   (M=512, K=512-m0)
        m0 = (id >> 2) * 128; n0 = (id & 3) * 128;
        Ab = Ycm + (long long)bz * IMG;     lda = 512;
        Cb = U   + (long long)bz * IMG;     ldc = 512;
        Keff = 512 - m0;
    } else if (id < 24) {     // S5: U2^T = Y2^T @ D[:256,:]  (M=256, K=256-m0)
        int t = id - 16;
        m0 = (t >> 2) * 128; n0 = (t & 3) * 128;
        Ab = Y2 + (long long)bz * 65536;    lda = 256;
        Cb = U2 + (long long)bz * 131072;   ldc = 256;
        Keff = 256 - m0;
    } else {                  // S7: U3^T = Y3^T @ D[:128,:]  (M=128, K=128)
        int t = id - 24;
        m0 = 0;              n0 = (t & 3) * 128;
        Ab = Y3 + (long long)bz * 16384;    lda = 128;
        Cb = U3 + (long long)bz * 65536;    ldc = 128;
        Keff = 128;
    }
    const u16* __restrict__ Bb = Dcm;
    const int ldb = 512;

    GEMM_DECLS
    GEMM_LOOP(Ab, lda, Bb, ldb, Keff)

    #pragma unroll
    for (int i = 0; i < 4; ++i)
        #pragma unroll
        for (int j = 0; j < 4; ++j) {
            int r = m0 + wr + i * 16 + rb;
            int c = n0 + wc + j * 16 + fr;
            ushort4 h;
            h.x = f2h(acc[i][j][0]); h.y = f2h(acc[i][j][1]);
            h.z = f2h(acc[i][j][2]); h.w = f2h(acc[i][j][3]);
            *(ushort4*)&Cb[(long long)c * ldc + r] = h;
        }
}

// ---------------------------------------------------------------------------
// invC: merged S6/S8/S4, fp32 row-major out. Flat blockIdx.x in [0,40):
// [0,16)=S6 (HL = U2 @ D[:256,:], K=256), [16,32)=S8 (LH = U3 @ D[:128,:],
// K=128), [32,40)=S4 (HH = U @ D, K=512) with TWO m-tiles per block
// (R13-proven amortization; pass-2 staging safe: all buf reads complete
// before pass-1's last pre-epilogue barrier, and the loop's own
// __syncthreads drains pass-2 loads).
// ---------------------------------------------------------------------------
__global__ __launch_bounds__(256, 4) void invC(
    const u16* __restrict__ U2, const u16* __restrict__ U3,
    const u16* __restrict__ U, const u16* __restrict__ Dcm,
    float* __restrict__ outHL, float* __restrict__ outLH,
    float* __restrict__ outHH)
{
    __shared__ u16 As[2][128 * 32];
    __shared__ u16 Bs[2][128 * 32];
    const int bz = blockIdx.z;
    const int id = blockIdx.x;

    const u16* __restrict__ Ab;
    float* __restrict__ Cb;
    int lda, Keff, m0base, n0, npass;
    if (id < 16) {            // S6: HL
        m0base = (id >> 2) * 128; n0 = (id & 3) * 128;
        Ab = U2 + (long long)bz * 131072;  lda = 256; Keff = 256;
        Cb = outHL + (long long)bz * IMG;  npass = 1;
    } else if (id < 32) {     // S8: LH
        int t = id - 16;
        m0base = (t >> 2) * 128; n0 = (t & 3) * 128;
        Ab = U3 + (long long)bz * 65536;   lda = 128; Keff = 128;
        Cb = outLH + (long long)bz * IMG;  npass = 1;
    } else {                  // S4: HH, 2 m-tiles per block
        int t = id - 32;                   // 0..7
        m0base = (t >> 2) * 256; n0 = (t & 3) * 128;
        Ab = U + (long long)bz * IMG;      lda = 512; Keff = 512;
        Cb = outHH + (long long)bz * IMG;  npass = 2;
    }
    const u16* __restrict__ Bb = Dcm;
    const int ldb = 512;
    const int ldc = 512;

    for (int pass = 0; pass < npass; ++pass) {
        const int m0 = m0base + pass * 128;
        GEMM_DECLS
        GEMM_LOOP(Ab, lda, Bb, ldb, Keff)

        #pragma unroll
        for (int i = 0; i < 4; ++i)
            #pragma unroll
            for (int j = 0; j < 4; ++j) {
                int r = m0 + wr + i * 16 + rb;
                int c = n0 + wc + j * 16 + fr;
                #pragma unroll
                for (int g = 0; g < 4; ++g)
                    Cb[(long long)(r + g) * ldc + c] = acc[i][j][g];
            }
        if (pass + 1 < npass) __syncthreads();
    }
}

// ---------------------------------------------------------------------------
// Orchestration (5 dispatches): conv -> S1 -> S2 -> invA -> invC.
// ws layout (ws_size ~1.5GiB per poison-fill evidence; we use 148MiB):
//   Drm @0 | Dcm @512K | Xcm/Ycm @1MiB (48MiB) |
//   reg @49MiB (48MiB): T1 (S1->S2) then U (invA->invC) |
//   Y2 @97MiB | Y3 @109MiB | U2 @112MiB | U3 @136MiB
// Race-freedom: invA reads Ycm/Y2/Y3, writes U/U2/U3 (disjoint); invC reads
// U/U2/U3 (read-only), writes the three d_out quarters (disjoint).
// ---------------------------------------------------------------------------
extern "C" void kernel_launch(void* const* d_in, const int* in_sizes, int n_in,
                              void* d_out, int out_size, void* d_ws, size_t ws_size,
                              hipStream_t stream) {
    const float* x = (const float*)d_in[0];
    float* out = (float*)d_out;
    float* outLL = out + 0 * OUT_PLANE;
    float* outLH = out + 1 * OUT_PLANE;
    float* outHL = out + 2 * OUT_PLANE;
    float* outHH = out + 3 * OUT_PLANE;

    char* ws = (char*)d_ws;
    u16* Drm = (u16*)(ws);
    u16* Dcm = (u16*)(ws + 524288);
    u16* Xcm = (u16*)(ws + 1048576);
    u16* Ycm = Xcm;
    char* reg = ws + 51380224;
    u16* T1 = (u16*)reg;
    u16* U  = (u16*)reg;
    u16* Y2 = (u16*)(ws + 101711872);      // 96*256*256 f16 = 12 MiB
    u16* Y3 = (u16*)(ws + 114294784);      // 96*128*128 f16 = 3 MiB
    u16* U2 = (u16*)(ws + 117440512);      // 96*512*256 f16 = 24 MiB
    u16* U3 = (u16*)(ws + 142606336);      // 96*512*128 f16 = 12 MiB

    const long long S = IMG;
    const int BIG = 1 << 30;

    // conv + D-build + LL copy
    conv_x<<<dim3(16, 16, NIMG), 256, 0, stream>>>(x, Xcm, outLL, Drm, Dcm);

    // S1: T1 = D @ X -> f16 row-major
    gemm16<1><<<dim3(4, 4, NIMG), 256, 0, stream>>>(
        Drm, 0, 512, Xcm, S, 512, T1, S, 512, 512, BIG, nullptr, nullptr);
    // S2: Y = T1 @ D^T -> Ycm (tri511) + Y2/Y3; compact grid (10 live tiles)
    gemm16<3><<<dim3(10, 1, NIMG), 256, 0, stream>>>(
        T1, S, 512, Drm, 0, 512, Ycm, S, 512, 512, 511, Y2, Y3);
    // invA: S3 + S5 + S7 -> U, U2, U3 (all ws)
    invA<<<dim3(28, 1, NIMG), 256, 0, stream>>>(Ycm, Y2, Y3, Dcm, U, U2, U3);
    // invC: S6 + S8 + S4(2-pass) -> outHL, outLH, outHH
    invC<<<dim3(40, 1, NIMG), 256, 0, stream>>>(U2, U3, U, Dcm, outHL, outLH, outHH);
}